// Round 11
// baseline (4047.858 us; speedup 1.0000x reference)
//
#include <hip/hip_runtime.h>
#include <hip/hip_bf16.h>
#include <hip/hip_cooperative_groups.h>
#include <math.h>

#define Bq 64
#define Sq 300
#define NH 4
#define DHd 32
#define Dd 128
#define NL 8
#define FF 512
#define NIN 36
#define SP 304   // padded seq for MFMA tiles
#define SPX 320  // j-range incl. last-tile overrun (10 tiles x 32)

namespace cg = cooperative_groups;

typedef __attribute__((ext_vector_type(8))) short bf16x8;
typedef __attribute__((ext_vector_type(4))) float f32x4;

__device__ __forceinline__ float gelu_f(float x) {
    return 0.5f * x * (1.0f + erff(x * 0.70710678118654752f));
}
__device__ __forceinline__ bool bf16_mode(const unsigned* maskw) {
    return maskw[0] == 0x3F803F80u;   // two bf16 1.0s; f32 1.0 is 0x3F800000
}

// -------- dtype-agnostic input widening: all 36 inputs -> fp32 shadow in ws --------
struct ConvArgs {
    const void* src[NIN];
    float* dst[NIN];
    int n[NIN];
};

__global__ void convert_kernel(ConvArgs a, const unsigned* maskw) {
    bool bfm = bf16_mode(maskw);
    int bi = blockIdx.y;
    int n = a.n[bi];
    float* dst = a.dst[bi];
    int stride = gridDim.x * blockDim.x;
    int i0 = blockIdx.x * blockDim.x + threadIdx.x;
    if (bfm) {
        const __hip_bfloat16* s = (const __hip_bfloat16*)a.src[bi];
        for (int i = i0; i < n; i += stride) dst[i] = __bfloat162float(s[i]);
    } else {
        const float* s = (const float*)a.src[bi];
        for (int i = i0; i < n; i += stride) dst[i] = s[i];
    }
}

// -------- pack weights to MFMA B-operand layout [nt][kt][64][8] bf16 --------
__global__ void pack_kernel(const float* __restrict__ W1all, const float* __restrict__ W2all,
                            const float* __restrict__ Wqall, const float* __restrict__ Woall,
                            const float* __restrict__ Wr1, const float* __restrict__ Wr2,
                            const float* __restrict__ We2, const float* __restrict__ We3,
                            __hip_bfloat16* __restrict__ P1, __hip_bfloat16* __restrict__ P2,
                            __hip_bfloat16* __restrict__ Pq, __hip_bfloat16* __restrict__ Po,
                            __hip_bfloat16* __restrict__ Pr1, __hip_bfloat16* __restrict__ Pr2,
                            __hip_bfloat16* __restrict__ Pe2, __hip_bfloat16* __restrict__ Pe3) {
    int l = blockIdx.y;
    int which = blockIdx.z;
    if (which >= 4 && l != 0) return;
    int K = (which == 1) ? 512 : ((which == 6) ? 64 : 128);
    int N = (which == 0) ? 512 : (which == 1 ? 128 : (which == 2 ? 384 : (which == 5 ? 64 : 128)));
    int slots = (K / 32) * (N / 16) * 64;
    int idx = blockIdx.x * 256 + threadIdx.x;
    if (idx >= slots) return;
    int lane = idx & 63;
    int nkt = K / 32;
    int kt = (idx >> 6) % nkt;
    int nt = (idx >> 6) / nkt;
    const float* W; __hip_bfloat16* P;
    switch (which) {
        case 0:  W = W1all + (size_t)l * 128 * 512; P = P1 + (size_t)l * 65536; break;
        case 1:  W = W2all + (size_t)l * 512 * 128; P = P2 + (size_t)l * 65536; break;
        case 2:  W = Wqall + (size_t)l * 128 * 384; P = Pq + (size_t)l * 49152; break;
        case 3:  W = Woall + (size_t)l * 128 * 128; P = Po + (size_t)l * 16384; break;
        case 4:  W = Wr1; P = Pr1; break;
        case 5:  W = Wr2; P = Pr2; break;
        case 6:  W = We2; P = Pe2; break;
        default: W = We3; P = Pe3; break;
    }
    P += (size_t)idx * 8;
    int n = nt * 16 + (lane & 15);
    int k0 = kt * 32 + (lane >> 4) * 8;
    #pragma unroll
    for (int j = 0; j < 8; j++) P[j] = __float2bfloat16(W[(size_t)(k0 + j) * N + n]);
}

// -------- embedding v3: MFMA for layers 2&3, fp32 layer1 --------
__global__ __launch_bounds__(256) void embed_mfma_kernel(
        const float* __restrict__ inp, const float* __restrict__ mask,
        const float* __restrict__ W1, const float* __restrict__ b1,
        const __hip_bfloat16* __restrict__ Pe2, const float* __restrict__ b2,
        const __hip_bfloat16* __restrict__ Pe3, const float* __restrict__ b3,
        const float* __restrict__ tok_emb,
        const float* __restrict__ ln_s, const float* __restrict__ ln_b,
        float* __restrict__ x) {
    int blk = blockIdx.x;       // 0..1199
    int t = threadIdx.x;        // 0..255
    int w = t >> 6, lane = t & 63;
    int row0 = blk * 16;
    __shared__ float f[16][4];
    __shared__ __align__(16) __hip_bfloat16 e1a[16 * 72];
    __shared__ __align__(16) __hip_bfloat16 e2a[16 * 136];
    __shared__ float dbuf[16 * 132];
    if (t < 64) f[t >> 2][t & 3] = inp[(size_t)(row0 + (t >> 2)) * 4 + (t & 3)];
    __syncthreads();
    {
        int r1 = t >> 4, n0 = (t & 15) * 4;
        float f0 = f[r1][0], f1 = f[r1][1], f2 = f[r1][2];
        #pragma unroll
        for (int j = 0; j < 4; j++) {
            int n = n0 + j;
            float a = b1[n] + f0 * W1[n] + f1 * W1[64 + n] + f2 * W1[128 + n];
            e1a[r1 * 72 + n] = __float2bfloat16(gelu_f(a));
        }
    }
    __syncthreads();
    int m = lane & 15, quad = lane >> 4;
    bf16x8 a2[2];
    #pragma unroll
    for (int kt = 0; kt < 2; kt++) a2[kt] = *(bf16x8*)&e1a[m * 72 + kt * 32 + quad * 8];
    #pragma unroll
    for (int nt0 = 0; nt0 < 2; nt0++) {
        int nt = w * 2 + nt0;
        f32x4 acc = {0.f, 0.f, 0.f, 0.f};
        const bf16x8* bp = (const bf16x8*)(Pe2 + (size_t)nt * 2 * 512);
        #pragma unroll
        for (int kt = 0; kt < 2; kt++) {
            bf16x8 bfr = bp[kt * 64 + lane];
            acc = __builtin_amdgcn_mfma_f32_16x16x32_bf16(a2[kt], bfr, acc, 0, 0, 0);
        }
        int n = nt * 16 + m;
        float bb = b2[n];
        #pragma unroll
        for (int r = 0; r < 4; r++)
            e2a[(quad * 4 + r) * 136 + n] = __float2bfloat16(gelu_f(acc[r] + bb));
    }
    __syncthreads();
    bf16x8 a3[4];
    #pragma unroll
    for (int kt = 0; kt < 4; kt++) a3[kt] = *(bf16x8*)&e2a[m * 136 + kt * 32 + quad * 8];
    f32x4 acc2[2] = {{0.f,0.f,0.f,0.f}, {0.f,0.f,0.f,0.f}};
    #pragma unroll
    for (int kt = 0; kt < 4; kt++) {
        #pragma unroll
        for (int nt0 = 0; nt0 < 2; nt0++) {
            int nt = w * 2 + nt0;
            bf16x8 bfr = ((const bf16x8*)(Pe3 + (size_t)nt * 4 * 512))[kt * 64 + lane];
            acc2[nt0] = __builtin_amdgcn_mfma_f32_16x16x32_bf16(a3[kt], bfr, acc2[nt0], 0, 0, 0);
        }
    }
    #pragma unroll
    for (int nt0 = 0; nt0 < 2; nt0++) {
        int n = (w * 2 + nt0) * 16 + m;
        float bb = b3[n];
        #pragma unroll
        for (int r = 0; r < 4; r++) {
            int row = quad * 4 + r;
            int tok = (int)f[row][3];
            dbuf[row * 132 + n] = gelu_f(acc2[nt0][r] + bb) + tok_emb[tok * 128 + n];
        }
    }
    __syncthreads();
    #pragma unroll
    for (int rr = 0; rr < 4; rr++) {
        int row = w * 4 + rr;
        int c0 = lane, c1 = lane + 64;
        float y0 = dbuf[row * 132 + c0];
        float y1 = dbuf[row * 132 + c1];
        float sm = y0 + y1;
        #pragma unroll
        for (int o = 32; o > 0; o >>= 1) sm += __shfl_xor(sm, o);
        float mu = sm * (1.0f / 128.0f);
        float d0 = y0 - mu, d1 = y1 - mu;
        float vv = d0 * d0 + d1 * d1;
        #pragma unroll
        for (int o = 32; o > 0; o >>= 1) vv += __shfl_xor(vv, o);
        float rstd = rsqrtf(vv * (1.0f / 128.0f) + 1e-7f);
        float mk = mask[row0 + row];
        x[(size_t)(row0 + row) * 128 + c0] = (d0 * rstd * ln_s[c0] + ln_b[c0]) * mk;
        x[(size_t)(row0 + row) * 128 + c1] = (d1 * rstd * ln_s[c1] + ln_b[c1]) * mk;
    }
}

// -------- qkv standalone (layer 0 only): 32 rows/block, 512 thr --------
__global__ __launch_bounds__(512) void qkv_mfma_kernel(const float* __restrict__ x,
                                                       const __hip_bfloat16* __restrict__ Pq,
                                                       const float* __restrict__ qb, const float* __restrict__ vb,
                                                       __hip_bfloat16* __restrict__ qbf,
                                                       __hip_bfloat16* __restrict__ kbf,
                                                       __hip_bfloat16* __restrict__ vT) {
    int blk = blockIdx.x;       // 0..599
    int t = threadIdx.x;        // 0..511
    int w = t >> 6, lane = t & 63;
    int row0 = blk * 32;
    __shared__ __align__(16) __hip_bfloat16 xa[32 * 136];
    for (int i = t; i < 1024; i += 512) {
        float4 v4 = ((const float4*)(x + (size_t)row0 * 128))[i];
        int r = i >> 5, c4 = (i & 31) * 4;
        __hip_bfloat16* d = &xa[r * 136 + c4];
        d[0] = __float2bfloat16(v4.x); d[1] = __float2bfloat16(v4.y);
        d[2] = __float2bfloat16(v4.z); d[3] = __float2bfloat16(v4.w);
    }
    __syncthreads();
    int m = lane & 15, quad = lane >> 4;
    bf16x8 a1[2][4];
    #pragma unroll
    for (int mt = 0; mt < 2; mt++)
        #pragma unroll
        for (int kt = 0; kt < 4; kt++)
            a1[mt][kt] = *(bf16x8*)&xa[(mt * 16 + m) * 136 + kt * 32 + quad * 8];
    const float inv_scale = 0.10206207261596576f;  // 1/sqrt(96)
    #pragma unroll
    for (int nt0 = 0; nt0 < 3; nt0++) {
        int nt = w * 3 + nt0;
        f32x4 acc[2] = {{0.f,0.f,0.f,0.f}, {0.f,0.f,0.f,0.f}};
        const bf16x8* bp = (const bf16x8*)(Pq + (size_t)nt * 4 * 512);
        #pragma unroll
        for (int kt = 0; kt < 4; kt++) {
            bf16x8 bfr = bp[kt * 64 + lane];
            #pragma unroll
            for (int mt = 0; mt < 2; mt++)
                acc[mt] = __builtin_amdgcn_mfma_f32_16x16x32_bf16(a1[mt][kt], bfr, acc[mt], 0, 0, 0);
        }
        int n = nt * 16 + m;
        int h = n / 96, mm = (n % 96) / 32, d = n % 32;
        float qbv = qb[h * 32 + d], vbv = vb[h * 32 + d];
        #pragma unroll
        for (int mt = 0; mt < 2; mt++) {
            #pragma unroll
            for (int r = 0; r < 4; r++) {
                int row = row0 + mt * 16 + quad * 4 + r;
                int bb = row / Sq, s = row % Sq;
                int bh = bb * NH + h;
                float a = acc[mt][r];
                if (mm == 0) {
                    qbf[((size_t)bh * SP + s) * 32 + d] = __float2bfloat16((a + qbv) * inv_scale);
                } else if (mm == 1) {
                    kbf[((size_t)bh * SP + s) * 32 + d] = __float2bfloat16(a);
                } else {
                    vT[((size_t)bh * 32 + d) * SP + s] = __float2bfloat16(a + vbv);
                }
            }
        }
    }
}

// -------- zero the never-written padding rows/cols (once, before layer loop) --------
__global__ void pad_kernel(__hip_bfloat16* qbf, __hip_bfloat16* kbf, __hip_bfloat16* vT) {
    int i = blockIdx.x * 256 + threadIdx.x;   // 256 bh * 4 s * 32 d = 32768
    if (i >= 256 * 4 * 32) return;
    int bh = i >> 7, s = Sq + ((i >> 5) & 3), d = i & 31;
    __hip_bfloat16 z = __float2bfloat16(0.0f);
    qbf[((size_t)bh * SP + s) * 32 + d] = z;
    kbf[((size_t)bh * SP + s) * 32 + d] = z;
    vT[((size_t)bh * 32 + d) * SP + s] = z;
}

// -------- positional projections -> bf16 MFMA-B layout [L][NH][16 r][32 d] --------
__global__ void pos_kernel(const float* __restrict__ rel_emb,
                           const float* __restrict__ pkW_all, const float* __restrict__ pqW_all,
                           const float* __restrict__ pqb_all,
                           __hip_bfloat16* __restrict__ poskb, __hip_bfloat16* __restrict__ posqb) {
    int l = blockIdx.y;         // 0..NL-1
    int bi = blockIdx.x;        // 0..31
    int which = bi >> 4;        // 0: posk, 1: posq
    int r = bi & 15;
    int t = threadIdx.x;        // 0..127 = h*32+d
    __shared__ float re[128];
    re[t] = rel_emb[r * 128 + t];
    __syncthreads();
    const float* W = (which ? pqW_all : pkW_all) + (size_t)l * 128 * 128;
    float a = 0.0f;
    for (int k = 0; k < 128; k++) a += re[k] * W[k * 128 + t];
    int h = t >> 5, d = t & 31;
    size_t o = ((size_t)(l * NH + h) * 16 + r) * 32 + d;
    if (which) { a = (a + pqb_all[l * 128 + t]) * 0.10206207261596576f; posqb[o] = __float2bfloat16(a); }
    else       { poskb[o] = __float2bfloat16(a); }
}

// ======== shared device bodies for attn and aoffn (used by both the ========
// ======== standalone kernels and the cooperative mega-kernel)       ========

__device__ __forceinline__ void attn_body(
        const __hip_bfloat16* __restrict__ qbf, const __hip_bfloat16* __restrict__ kbf,
        const __hip_bfloat16* __restrict__ vT,
        const __hip_bfloat16* __restrict__ poskb, const __hip_bfloat16* __restrict__ posqb,
        const float* __restrict__ mask, __hip_bfloat16* __restrict__ ctxb,
        int bh, int yb,
        float* p2cS, float* c2pS, __hip_bfloat16* pT) {
    int b = bh >> 2, h = bh & 3;
    int t = threadIdx.x;
    int w = t >> 6, lane = t & 63;
    int m = lane & 15, quad = lane >> 4;

    // ---- stage p2cS[j][r] = k[j].posq[r] via MFMA, mask/padding folded to -3e4 ----
    {
        bf16x8 pqf = *(const bf16x8*)&posqb[(h * 16 + m) * 32 + quad * 8];
        #pragma unroll
        for (int it = 0; it < 5; it++) {
            int jb = (w + it * 4) * 16;
            bf16x8 kf2 = *(const bf16x8*)&kbf[((size_t)bh * SP + jb + m) * 32 + quad * 8];
            f32x4 pc = __builtin_amdgcn_mfma_f32_16x16x32_bf16(kf2, pqf, (f32x4){0.f,0.f,0.f,0.f}, 0, 0, 0);
            #pragma unroll
            for (int r = 0; r < 4; r++) {
                int j = jb + quad * 4 + r;
                float mv = (j < Sq) ? mask[b * Sq + j] : 0.0f;
                p2cS[j * 17 + m] = (mv > 0.0f) ? pc[r] : -30000.0f;
            }
        }
    }
    __syncthreads();

    int qt = yb * 4 + w;            // 0..19
    if (qt < 19) {
        int q0 = qt * 16;
        float* c2pW = c2pS + w * (16 * 17);
        __hip_bfloat16* pTW = pT + w * (16 * 40);

        bf16x8 aq = *(const bf16x8*)&qbf[((size_t)bh * SP + q0 + m) * 32 + quad * 8];

        {
            bf16x8 pkf = *(const bf16x8*)&poskb[(h * 16 + m) * 32 + quad * 8];
            f32x4 cc = __builtin_amdgcn_mfma_f32_16x16x32_bf16(aq, pkf, (f32x4){0.f,0.f,0.f,0.f}, 0, 0, 0);
            #pragma unroll
            for (int r = 0; r < 4; r++) c2pW[(quad * 4 + r) * 17 + m] = cc[r];
        }

        int qi = q0 + m;
        f32x4 oacc[2] = {{0.f,0.f,0.f,0.f}, {0.f,0.f,0.f,0.f}};
        float lacc = 0.0f;

        for (int jt2 = 0; jt2 < 10; jt2++) {
            int j0 = jt2 * 32;
            #pragma unroll
            for (int half = 0; half < 2; half++) {
                int jh = j0 + half * 16;
                bf16x8 kf = *(const bf16x8*)&kbf[((size_t)bh * SP + jh + m) * 32 + quad * 8];
                f32x4 sc = __builtin_amdgcn_mfma_f32_16x16x32_bf16(kf, aq, (f32x4){0.f,0.f,0.f,0.f}, 0, 0, 0);
                int jb2 = jh + quad * 4;
                int base = qi - jb2 + 8;
                __hip_bfloat16 pb[4];
                #pragma unroll
                for (int r = 0; r < 4; r++) {
                    int rr = base - r; rr = rr < 0 ? 0 : (rr > 15 ? 15 : rr);
                    float sv = sc[r] + c2pW[m * 17 + rr] + p2cS[(jb2 + r) * 17 + rr];
                    float p = __expf(sv);
                    lacc += p;
                    pb[r] = __float2bfloat16(p);
                }
                *(uint2*)&pTW[m * 40 + half * 16 + quad * 4] = *(uint2*)pb;
            }
            bf16x8 ap = *(bf16x8*)&pTW[m * 40 + quad * 8];
            #pragma unroll
            for (int nt = 0; nt < 2; nt++) {
                bf16x8 vf = *(const bf16x8*)&vT[((size_t)bh * 32 + nt * 16 + m) * SP + j0 + quad * 8];
                oacc[nt] = __builtin_amdgcn_mfma_f32_16x16x32_bf16(ap, vf, oacc[nt], 0, 0, 0);
            }
        }

        lacc += __shfl_xor(lacc, 16);
        lacc += __shfl_xor(lacc, 32);
        #pragma unroll
        for (int r = 0; r < 4; r++) {
            int qrow = quad * 4 + r;
            float lr = __shfl(lacc, qrow);
            int qi2 = q0 + qrow;
            float qm = (qi2 < Sq) ? mask[b * Sq + qi2] : 0.0f;
            float inv = (qm > 0.0f && lr > 0.0f) ? 1.0f / lr : 0.0f;
            if (qi2 < Sq) {
                size_t base2 = ((size_t)(b * Sq + qi2)) * 128 + h * 32;
                ctxb[base2 + m]      = __float2bfloat16(oacc[0][r] * inv);
                ctxb[base2 + 16 + m] = __float2bfloat16(oacc[1][r] * inv);
            }
        }
    }
}

__device__ __forceinline__ void aoffn_body(
        const __hip_bfloat16* __restrict__ ctxb,
        const __hip_bfloat16* __restrict__ Po, const float* __restrict__ ob,
        const float* __restrict__ ln1s, const float* __restrict__ ln1b,
        const __hip_bfloat16* __restrict__ P1, const float* __restrict__ b1,
        const __hip_bfloat16* __restrict__ P2, const float* __restrict__ b2,
        const float* __restrict__ ln2s, const float* __restrict__ ln2b,
        float* __restrict__ x,
        int do_qkv,
        const __hip_bfloat16* __restrict__ Pqn,
        const float* __restrict__ qbn, const float* __restrict__ vbn,
        __hip_bfloat16* __restrict__ qbf, __hip_bfloat16* __restrict__ kbf,
        __hip_bfloat16* __restrict__ vT,
        int blk, __hip_bfloat16* ca, char* hbuf) {
    int t = threadIdx.x;        // 0..255
    int w = t >> 6, lane = t & 63;
    int row0 = blk * 16;

    __hip_bfloat16* ha = (__hip_bfloat16*)hbuf;             // [16][520]
    float* dbuf = (float*)hbuf;                             // [16][132]

    {   // stage ctx (bf16 direct): 16*128 bf16 = 256 thr x 8
        uint4 cv = ((const uint4*)(ctxb + (size_t)row0 * 128))[t];
        int r = t >> 4, c8 = (t & 15) * 8;
        *(uint4*)&ca[r * 136 + c8] = cv;
    }
    __syncthreads();

    int m = lane & 15, quad = lane >> 4;

    // ---- attn_out matmul: K=128, N=128; 2 nt/wave ----
    {
        bf16x8 a1[4];
        #pragma unroll
        for (int kt = 0; kt < 4; kt++) a1[kt] = *(bf16x8*)&ca[m * 136 + kt * 32 + quad * 8];
        f32x4 acc2[2] = {{0.f,0.f,0.f,0.f}, {0.f,0.f,0.f,0.f}};
        #pragma unroll
        for (int kt = 0; kt < 4; kt++) {
            #pragma unroll
            for (int nt0 = 0; nt0 < 2; nt0++) {
                int nt = w * 2 + nt0;
                bf16x8 bfr = ((const bf16x8*)(Po + (size_t)nt * 4 * 512))[kt * 64 + lane];
                acc2[nt0] = __builtin_amdgcn_mfma_f32_16x16x32_bf16(a1[kt], bfr, acc2[nt0], 0, 0, 0);
            }
        }
        #pragma unroll
        for (int nt0 = 0; nt0 < 2; nt0++) {
            int n = (w * 2 + nt0) * 16 + m;
            #pragma unroll
            for (int r = 0; r < 4; r++) dbuf[(quad * 4 + r) * 132 + n] = acc2[nt0][r];
        }
    }
    __syncthreads();

    // ---- LN1 (+residual, x read from global) -> registers + ca (bf16) ----
    float x1a[4], x1b[4];
    #pragma unroll
    for (int rr = 0; rr < 4; rr++) {
        int row = w * 4 + rr;
        int c0 = lane, c1 = lane + 64;
        size_t g = (size_t)(row0 + row) * 128;
        float y0 = dbuf[row * 132 + c0] + ob[c0] + x[g + c0];
        float y1 = dbuf[row * 132 + c1] + ob[c1] + x[g + c1];
        float sm = y0 + y1;
        #pragma unroll
        for (int o = 32; o > 0; o >>= 1) sm += __shfl_xor(sm, o);
        float mu = sm * (1.0f / 128.0f);
        float d0 = y0 - mu, d1 = y1 - mu;
        float vv = d0 * d0 + d1 * d1;
        #pragma unroll
        for (int o = 32; o > 0; o >>= 1) vv += __shfl_xor(vv, o);
        float rstd = rsqrtf(vv * (1.0f / 128.0f) + 1e-7f);
        float o0 = d0 * rstd * ln1s[c0] + ln1b[c0];
        float o1 = d1 * rstd * ln1s[c1] + ln1b[c1];
        x1a[rr] = o0;
        x1b[rr] = o1;
        ca[row * 136 + c0] = __float2bfloat16(o0);
        ca[row * 136 + c1] = __float2bfloat16(o1);
    }
    __syncthreads();

    // ---- FFN phase 1: h = gelu(x1 @ W1 + b1); N=512, 8 nt/wave ----
    {
        bf16x8 a1[4];
        #pragma unroll
        for (int kt = 0; kt < 4; kt++)
            a1[kt] = *(bf16x8*)&ca[m * 136 + kt * 32 + quad * 8];
        #pragma unroll
        for (int nt0 = 0; nt0 < 8; nt0++) {
            int nt = w * 8 + nt0;
            f32x4 acc = {0.f, 0.f, 0.f, 0.f};
            const bf16x8* bp = (const bf16x8*)(P1 + (size_t)nt * 4 * 512);
            #pragma unroll
            for (int kt = 0; kt < 4; kt++) {
                bf16x8 bfr = bp[kt * 64 + lane];
                acc = __builtin_amdgcn_mfma_f32_16x16x32_bf16(a1[kt], bfr, acc, 0, 0, 0);
            }
            int n = nt * 16 + m;
            float bb = b1[n];
            #pragma unroll
            for (int r = 0; r < 4; r++)
                ha[(quad * 4 + r) * 520 + n] = __float2bfloat16(gelu_f(acc[r] + bb));
        }
    }
    __syncthreads();

    // ---- FFN phase 2: K=512 (16 kt), N=128 (2 nt/wave) ----
    f32x4 acc2[2] = {{0.f,0.f,0.f,0.f}, {0.f,0.f,0.f,0.f}};
    #pragma unroll
    for (int kt = 0; kt < 16; kt++) {
        bf16x8 a = *(bf16x8*)&ha[m * 520 + kt * 32 + quad * 8];
        #pragma unroll
        for (int nt0 = 0; nt0 < 2; nt0++) {
            int nt = w * 2 + nt0;
            bf16x8 bfr = ((const bf16x8*)(P2 + (size_t)nt * 16 * 512))[kt * 64 + lane];
            acc2[nt0] = __builtin_amdgcn_mfma_f32_16x16x32_bf16(a, bfr, acc2[nt0], 0, 0, 0);
        }
    }
    __syncthreads();            // all waves done READING ha; dbuf may overwrite
    #pragma unroll
    for (int nt0 = 0; nt0 < 2; nt0++) {
        int n = (w * 2 + nt0) * 16 + m;
        #pragma unroll
        for (int r = 0; r < 4; r++)
            dbuf[(quad * 4 + r) * 132 + n] = acc2[nt0][r];
    }
    __syncthreads();

    // ---- LN2 (+residual x1 from registers) -> x global, and x2 bf16 into ca ----
    #pragma unroll
    for (int rr = 0; rr < 4; rr++) {
        int row = w * 4 + rr;
        int c0 = lane, c1 = lane + 64;
        float y0 = dbuf[row * 132 + c0] + b2[c0] + x1a[rr];
        float y1 = dbuf[row * 132 + c1] + b2[c1] + x1b[rr];
        float sm = y0 + y1;
        #pragma unroll
        for (int o = 32; o > 0; o >>= 1) sm += __shfl_xor(sm, o);
        float mu = sm * (1.0f / 128.0f);
        float d0 = y0 - mu, d1 = y1 - mu;
        float vv = d0 * d0 + d1 * d1;
        #pragma unroll
        for (int o = 32; o > 0; o >>= 1) vv += __shfl_xor(vv, o);
        float rstd = rsqrtf(vv * (1.0f / 128.0f) + 1e-7f);
        float o0 = d0 * rstd * ln2s[c0] + ln2b[c0];
        float o1 = d1 * rstd * ln2s[c1] + ln2b[c1];
        x[(size_t)(row0 + row) * 128 + c0] = o0;
        x[(size_t)(row0 + row) * 128 + c1] = o1;
        ca[row * 136 + c0] = __float2bfloat16(o0);
        ca[row * 136 + c1] = __float2bfloat16(o1);
    }
    if (do_qkv) {
        __syncthreads();
        // ---- next-layer qkv: K=128, N=384; 6 nt/wave ----
        bf16x8 aq[4];
        #pragma unroll
        for (int kt = 0; kt < 4; kt++) aq[kt] = *(bf16x8*)&ca[m * 136 + kt * 32 + quad * 8];
        const float inv_scale = 0.10206207261596576f;  // 1/sqrt(96)
        #pragma unroll
        for (int nt0 = 0; nt0 < 6; nt0++) {
            int nt = w * 6 + nt0;
            f32x4 acc = {0.f, 0.f, 0.f, 0.f};
            const bf16x8* bp = (const bf16x8*)(Pqn + (size_t)nt * 4 * 512);
            #pragma unroll
            for (int kt = 0; kt < 4; kt++) {
                bf16x8 bfr = bp[kt * 64 + lane];
                acc = __builtin_amdgcn_mfma_f32_16x16x32_bf16(aq[kt], bfr, acc, 0, 0, 0);
            }
            int n = nt * 16 + m;
            int h = n / 96, mm = (n % 96) / 32, d = n % 32;
            float qbv = qbn[h * 32 + d], vbv = vbn[h * 32 + d];
            #pragma unroll
            for (int r = 0; r < 4; r++) {
                int row = row0 + quad * 4 + r;
                int bb = row / Sq, s = row % Sq;
                int bh = bb * NH + h;
                float a = acc[r];
                if (mm == 0) {
                    qbf[((size_t)bh * SP + s) * 32 + d] = __float2bfloat16((a + qbv) * inv_scale);
                } else if (mm == 1) {
                    kbf[((size_t)bh * SP + s) * 32 + d] = __float2bfloat16(a);
                } else {
                    vT[((size_t)bh * 32 + d) * SP + s] = __float2bfloat16(a + vbv);
                }
            }
        }
    }
}

// -------- standalone kernels (fallback path) --------
__global__ __launch_bounds__(256) void attn_mfma_kernel(const __hip_bfloat16* __restrict__ qbf,
                                                        const __hip_bfloat16* __restrict__ kbf,
                                                        const __hip_bfloat16* __restrict__ vT,
                                                        const __hip_bfloat16* __restrict__ poskb,
                                                        const __hip_bfloat16* __restrict__ posqb,
                                                        const float* __restrict__ mask,
                                                        __hip_bfloat16* __restrict__ ctxb) {
    __shared__ __align__(16) char smem[SPX * 17 * 4 + 4 * 16 * 17 * 4 + 4 * 16 * 40 * 2];
    float* p2cS = (float*)smem;
    float* c2pS = (float*)(smem + SPX * 17 * 4);
    __hip_bfloat16* pT = (__hip_bfloat16*)(smem + SPX * 17 * 4 + 4 * 16 * 17 * 4);
    attn_body(qbf, kbf, vT, poskb, posqb, mask, ctxb, blockIdx.x, blockIdx.y, p2cS, c2pS, pT);
}

__global__ __launch_bounds__(256) void aoffn_mfma_kernel(
        const __hip_bfloat16* __restrict__ ctxb,
        const __hip_bfloat16* __restrict__ Po, const float* __restrict__ ob,
        const float* __restrict__ ln1s, const float* __restrict__ ln1b,
        const __hip_bfloat16* __restrict__ P1, const float* __restrict__ b1,
        const __hip_bfloat16* __restrict__ P2, const float* __restrict__ b2,
        const float* __restrict__ ln2s, const float* __restrict__ ln2b,
        float* __restrict__ x, int do_qkv,
        const __hip_bfloat16* __restrict__ Pqn,
        const float* __restrict__ qbn, const float* __restrict__ vbn,
        __hip_bfloat16* __restrict__ qbf, __hip_bfloat16* __restrict__ kbf,
        __hip_bfloat16* __restrict__ vT) {
    __shared__ __align__(16) char smem[16 * 136 * 2 + 16 * 520 * 2];
    __hip_bfloat16* ca = (__hip_bfloat16*)smem;
    char* hbuf = smem + 16 * 136 * 2;
    aoffn_body(ctxb, Po, ob, ln1s, ln1b, P1, b1, P2, b2, ln2s, ln2b, x,
               do_qkv, Pqn, qbn, vbn, qbf, kbf, vT, blockIdx.x, ca, hbuf);
}

// -------- cooperative mega-kernel: all 8 layers, grid.sync between phases --------
struct MegaArgs {
    const __hip_bfloat16* Pkb; const __hip_bfloat16* Pqb;
    const float* mask;
    __hip_bfloat16* qbf; __hip_bfloat16* kbf; __hip_bfloat16* vT;
    __hip_bfloat16* ctxb;
    const __hip_bfloat16* Po; const float* ob;
    const float* ln1s; const float* ln1b;
    const __hip_bfloat16* P1; const float* b1;
    const __hip_bfloat16* P2; const float* b2;
    const float* ln2s; const float* ln2b;
    float* x;
    const __hip_bfloat16* Pq; const float* qb; const float* vb;
};

#define MEGA_GRID 1200

__global__ __launch_bounds__(256, 5) void mega_kernel(MegaArgs A) {
    cg::grid_group grid = cg::this_grid();
    // union of attn (31232 B) and aoffn (20992 B) LDS footprints
    __shared__ __align__(16) char smem[SPX * 17 * 4 + 4 * 16 * 17 * 4 + 4 * 16 * 40 * 2];
    float* p2cS = (float*)smem;
    float* c2pS = (float*)(smem + SPX * 17 * 4);
    __hip_bfloat16* pT = (__hip_bfloat16*)(smem + SPX * 17 * 4 + 4 * 16 * 17 * 4);
    __hip_bfloat16* ca = (__hip_bfloat16*)smem;
    char* hbuf = smem + 16 * 136 * 2;

    for (int l = 0; l < NL; l++) {
        // ---- attn phase: 1280 units on 1200 blocks ----
        {
            int u = blockIdx.x;
            attn_body(A.qbf, A.kbf, A.vT, A.Pkb + (size_t)l * 2048, A.Pqb + (size_t)l * 2048,
                      A.mask, A.ctxb, u & 255, u >> 8, p2cS, c2pS, pT);
            if (blockIdx.x < 80) {
                __syncthreads();
                int u2 = MEGA_GRID + blockIdx.x;
                attn_body(A.qbf, A.kbf, A.vT, A.Pkb + (size_t)l * 2048, A.Pqb + (size_t)l * 2048,
                          A.mask, A.ctxb, u2 & 255, u2 >> 8, p2cS, c2pS, pT);
            }
        }
        grid.sync();
        // ---- aoffn (+next-layer qkv) phase ----
        {
            int ln = (l + 1 < NL) ? (l + 1) : 0;
            aoffn_body(A.ctxb,
                       A.Po + (size_t)l * 16384, A.ob + l * 128,
                       A.ln1s + l * 128, A.ln1b + l * 128,
                       A.P1 + (size_t)l * 65536, A.b1 + l * 512,
                       A.P2 + (size_t)l * 65536, A.b2 + l * 128,
                       A.ln2s + l * 128, A.ln2b + l * 128, A.x,
                       (l + 1 < NL) ? 1 : 0,
                       A.Pq + (size_t)ln * 49152, A.qb + ln * 128, A.vb + ln * 128,
                       A.qbf, A.kbf, A.vT, blockIdx.x, ca, hbuf);
        }
        grid.sync();
    }
}

// -------- reconstruction MLP via MFMA: 16 rows/block; 128->128->64->5 --------
__global__ __launch_bounds__(256) void rec_mfma_kernel(const float* __restrict__ x,
                                                       const __hip_bfloat16* __restrict__ Pr1,
                                                       const float* __restrict__ b1,
                                                       const __hip_bfloat16* __restrict__ Pr2,
                                                       const float* __restrict__ b2,
                                                       const float* __restrict__ W3, const float* __restrict__ b3,
                                                       float* __restrict__ r3) {
    int blk = blockIdx.x;       // 0..1199
    int t = threadIdx.x;        // 0..255
    int w = t >> 6, lane = t & 63;
    int row0 = blk * 16;
    __shared__ __align__(16) __hip_bfloat16 xa[16 * 136];
    __shared__ __align__(16) __hip_bfloat16 ha[16 * 136];
    __shared__ float r2s[16 * 68];
    for (int i = t; i < 512; i += 256) {
        float4 v4 = ((const float4*)(x + (size_t)row0 * 128))[i];
        int r = i >> 5, c4 = (i & 31) * 4;
        __hip_bfloat16* d = &xa[r * 136 + c4];
        d[0] = __float2bfloat16(v4.x); d[1] = __float2bfloat16(v4.y);
        d[2] = __float2bfloat16(v4.z); d[3] = __float2bfloat16(v4.w);
    }
    __syncthreads();
    int m = lane & 15, quad = lane >> 4;

    bf16x8 a1[4];
    #pragma unroll
    for (int kt = 0; kt < 4; kt++) a1[kt] = *(bf16x8*)&xa[m * 136 + kt * 32 + quad * 8];
    #pragma unroll
    for (int nt0 = 0; nt0 < 2; nt0++) {
        int nt = w * 2 + nt0;
        f32x4 acc = {0.f, 0.f, 0.f, 0.f};
        const bf16x8* bp = (const bf16x8*)(Pr1 + (size_t)nt * 4 * 512);
        #pragma unroll
        for (int kt = 0; kt < 4; kt++) {
            bf16x8 bfr = bp[kt * 64 + lane];
            acc = __builtin_amdgcn_mfma_f32_16x16x32_bf16(a1[kt], bfr, acc, 0, 0, 0);
        }
        int n = nt * 16 + m;
        float bb = b1[n];
        #pragma unroll
        for (int r = 0; r < 4; r++)
            ha[(quad * 4 + r) * 136 + n] = __float2bfloat16(gelu_f(acc[r] + bb));
    }
    __syncthreads();

    {
        f32x4 acc = {0.f, 0.f, 0.f, 0.f};
        const bf16x8* bp = (const bf16x8*)(Pr2 + (size_t)w * 4 * 512);
        #pragma unroll
        for (int kt = 0; kt < 4; kt++) {
            bf16x8 a = *(bf16x8*)&ha[m * 136 + kt * 32 + quad * 8];
            bf16x8 bfr = bp[kt * 64 + lane];
            acc = __builtin_amdgcn_mfma_f32_16x16x32_bf16(a, bfr, acc, 0, 0, 0);
        }
        int n = w * 16 + m;
        float bb = b2[n];
        #pragma unroll
        for (int r = 0; r < 4; r++)
            r2s[(quad * 4 + r) * 68 + n] = gelu_f(acc[r] + bb);
    }
    __syncthreads();

    if (t < 80) {
        int row = t / 5, c = t % 5;
        float a = b3[c];
        for (int k = 0; k < 64; k++) a += r2s[row * 68 + k] * W3[k * 5 + c];
        r3[(size_t)(row0 + row) * 5 + c] = gelu_f(a);
    }
}

// -------- connection head v2 (R15 win, unchanged) --------
__global__ void conn_kernel(const float* __restrict__ r3, const float* __restrict__ W,
                            const float* __restrict__ b, void* out, const unsigned* maskw) {
    bool bfm = bf16_mode(maskw);
    int cb = blockIdx.x;     // 0..39
    int bg = blockIdx.y;     // 0..15
    int t = threadIdx.x;     // 0..255
    int cl = t & 63;
    int kq = t >> 6;
    int col = cb * 64 + cl;
    __shared__ float rs[4 * 1500];
    __shared__ float pacc[4 * 64 * 4];
    {
        const float4* src = (const float4*)(r3 + (size_t)bg * 4 * 1500);
        for (int i = t; i < 1500; i += 256) ((float4*)rs)[i] = src[i];
    }
    __syncthreads();
    float acc[4] = {0.f, 0.f, 0.f, 0.f};
    if (col < 2500) {
        for (int k = kq * 4; k < 1500; k += 16) {
            float w0 = W[(size_t)(k + 0) * 2500 + col];
            float w1 = W[(size_t)(k + 1) * 2500 + col];
            float w2 = W[(size_t)(k + 2) * 2500 + col];
            float w3 = W[(size_t)(k + 3) * 2500 + col];
            #pragma unroll
            for (int bb = 0; bb < 4; bb++) {
                float4 rv = *(const float4*)&rs[bb * 1500 + k];
                acc[bb] += rv.x * w0 + rv.y * w1 + rv.z * w2 + rv.w * w3;
            }
        }
    }
    #pragma unroll
    for (int bb = 0; bb < 4; bb++) pacc[(kq * 64 + cl) * 4 + bb] = acc[bb];
    __syncthreads();
    if (kq == 0 && col < 2500) {
        float bv = b[col];
        #pragma unroll
        for (int bb = 0; bb < 4; bb++) {
            float a = bv + pacc[(0 * 64 + cl) * 4 + bb] + pacc[(1 * 64 + cl) * 4 + bb]
                         + pacc[(2 * 64 + cl) * 4 + bb] + pacc[(3 * 64 + cl) * 4 + bb];
            int ob = bg * 4 + bb;
            if (bfm) ((__hip_bfloat16*)out)[(size_t)ob * 2500 + col] = __float2bfloat16(a);
            else     ((float*)out)[(size_t)ob * 2500 + col] = a;
        }
    }
}

extern "C" void kernel_launch(void* const* d_in, const int* in_sizes, int n_in,
                              void* d_out, int out_size, void* d_ws, size_t ws_size,
                              hipStream_t stream) {
    float* ws = (float*)d_ws;

    float* cv[NIN];
    size_t off = 0;
    for (int i = 0; i < NIN; i++) { cv[i] = ws + off; off += (size_t)in_sizes[i]; }

    const float* inp      = cv[0];
    const float* mask     = cv[1];
    const float* emb_W1   = cv[2];
    const float* emb_b1   = cv[3];
    const float* emb_W2   = cv[4];
    const float* emb_b2   = cv[5];
    const float* emb_W3   = cv[6];
    const float* emb_b3   = cv[7];
    const float* tok_emb  = cv[8];
    const float* emb_ln_s = cv[9];
    const float* emb_ln_b = cv[10];
    const float* rel_emb  = cv[11];
    const float* qkv_W    = cv[12];
    const float* q_bias   = cv[13];
    const float* v_bias   = cv[14];
    const float* pos_k_W  = cv[15];
    const float* pos_q_W  = cv[16];
    const float* pos_q_b  = cv[17];
    const float* attn_out_W = cv[18];
    const float* attn_out_b = cv[19];
    const float* ln1_s    = cv[20];
    const float* ln1_b    = cv[21];
    const float* ffn_W1   = cv[22];
    const float* ffn_b1   = cv[23];
    const float* ffn_W2   = cv[24];
    const float* ffn_b2   = cv[25];
    const float* ln2_s    = cv[26];
    const float* ln2_b    = cv[27];
    const float* rec_W1   = cv[28];
    const float* rec_b1   = cv[29];
    const float* rec_W2   = cv[30];
    const float* rec_b2   = cv[31];
    const float* rec_W3   = cv[32];
    const float* rec_b3   = cv[33];
    const float* conn_W   = cv[34];
    const float* conn_b   = cv[35];

    const int NTOK = Bq * Sq;            // 19200
    float* x    = ws + off;
    float* q    = x    + (size_t)NTOK * 128;             // (unused, kept for layout)
    float* k    = q    + (size_t)Bq * NH * Sq * 32;      // (unused)
    float* ctx  = k    + (size_t)Bq * NH * Sq * 32;      // reused as bf16 ctx
    float* c2p  = ctx  + (size_t)NTOK * 128;             // (unused)
    float* p2c  = c2p  + (size_t)Bq * NH * Sq * 16;      // (unused)
    float* posk = p2c  + (size_t)Bq * NH * Sq * 16;      // (unused)
    float* posq = posk + (size_t)NL * 16 * 128;          // (unused)
    float* r3b  = posq + (size_t)NL * 16 * 128;
    float* endf = r3b  + (size_t)NTOK * 5;
    __hip_bfloat16* P1 = (__hip_bfloat16*)endf;          // 8 x 65536 bf16
    __hip_bfloat16* P2 = P1 + (size_t)NL * 65536;
    __hip_bfloat16* Pq = P2 + (size_t)NL * 65536;        // 8 x 49152
    __hip_bfloat16* Po = Pq + (size_t)NL * 49152;        // 8 x 16384
    __hip_bfloat16* qbf = Po + (size_t)NL * 16384;       // 256*SP*32 each
    __hip_bfloat16* kbf = qbf + (size_t)256 * SP * 32;
    __hip_bfloat16* vTb = kbf + (size_t)256 * SP * 32;
    __hip_bfloat16* Pr1 = vTb + (size_t)256 * SP * 32;   // 16384
    __hip_bfloat16* Pr2 = Pr1 + 16384;                   // 8192
    __hip_bfloat16* Pe2 = Pr2 + 8192;                    // 8192
    __hip_bfloat16* Pe3 = Pe2 + 8192;                    // 16384
    __hip_bfloat16* Pkb = Pe3 + 16384;                   // [NL][NH][16][32] = 16384
    __hip_bfloat16* Pqb = Pkb + (size_t)NL * 2048;       // same
    __hip_bfloat16* ctxb = (__hip_bfloat16*)ctx;         // bf16 ctx [NTOK][128]

    const unsigned* maskw = (const unsigned*)d_in[1];

    ConvArgs ca;
    for (int i = 0; i < NIN; i++) {
        ca.src[i] = d_in[i];
        ca.dst[i] = cv[i];
        ca.n[i] = in_sizes[i];
    }
    convert_kernel<<<dim3(256, NIN), 256, 0, stream>>>(ca, maskw);
    pack_kernel<<<dim3(32, NL, 8), 256, 0, stream>>>(ffn_W1, ffn_W2, qkv_W, attn_out_W,
                                                     rec_W1, rec_W2, emb_W2, emb_W3,
                                                     P1, P2, Pq, Po, Pr1, Pr2, Pe2, Pe3);

    embed_mfma_kernel<<<NTOK / 16, 256, 0, stream>>>(inp, mask, emb_W1, emb_b1,
                                                     Pe2, emb_b2, Pe3, emb_b3,
                                                     tok_emb, emb_ln_s, emb_ln_b, x);

    pos_kernel<<<dim3(32, NL), 128, 0, stream>>>(rel_emb, pos_k_W, pos_q_W, pos_q_b, Pkb, Pqb);
    pad_kernel<<<128, 256, 0, stream>>>(qbf, kbf, vTb);

    // layer-0 qkv (standalone); layers 1..7 get qkv fused into the previous aoffn
    qkv_mfma_kernel<<<NTOK / 32, 512, 0, stream>>>(x, Pq, q_bias, v_bias, qbf, kbf, vTb);

    // ---- cooperative mega-kernel for the whole layer loop; fallback to per-kernel ----
    MegaArgs margs;
    margs.Pkb = Pkb; margs.Pqb = Pqb; margs.mask = mask;
    margs.qbf = qbf; margs.kbf = kbf; margs.vT = vTb; margs.ctxb = ctxb;
    margs.Po = Po; margs.ob = attn_out_b;
    margs.ln1s = ln1_s; margs.ln1b = ln1_b;
    margs.P1 = P1; margs.b1 = ffn_b1;
    margs.P2 = P2; margs.b2 = ffn_b2;
    margs.ln2s = ln2_s; margs.ln2b = ln2_b;
    margs.x = x;
    margs.Pq = Pq; margs.qb = q_bias; margs.vb = v_bias;
    void* kargs[] = { (void*)&margs };
    hipError_t cerr = hipLaunchCooperativeKernel(reinterpret_cast<void*>(mega_kernel),
                                                 dim3(MEGA_GRID), dim3(256), kargs, 0, stream);
    if (cerr != hipSuccess) {
        (void)hipGetLastError();   // clear sticky error, run fallback path
        for (int l = 0; l < NL; l++) {
            attn_mfma_kernel<<<dim3(256, 5), 256, 0, stream>>>(qbf, kbf, vTb,
                                                               Pkb + (size_t)l * 2048,
                                                               Pqb + (size_t)l * 2048,
                                                               mask, ctxb);
            int ln = (l + 1 < NL) ? (l + 1) : 0;
            aoffn_mfma_kernel<<<NTOK / 16, 256, 0, stream>>>(ctxb,
                                                             Po + (size_t)l * 16384, attn_out_b + l * 128,
                                                             ln1_s + l * 128, ln1_b + l * 128,
                                                             P1 + (size_t)l * 65536, ffn_b1 + l * 512,
                                                             P2 + (size_t)l * 65536, ffn_b2 + l * 128,
                                                             ln2_s + l * 128, ln2_b + l * 128, x,
                                                             (l + 1 < NL) ? 1 : 0,
                                                             Pq + (size_t)ln * 49152,
                                                             q_bias + ln * 128, v_bias + ln * 128,
                                                             qbf, kbf, vTb);
        }
    }

    rec_mfma_kernel<<<NTOK / 16, 256, 0, stream>>>(x, Pr1, rec_b1, Pr2, rec_b2,
                                                   rec_W3, rec_b3, r3b);
    conn_kernel<<<dim3(40, 16), 256, 0, stream>>>(r3b, conn_W, conn_b, d_out, maskw);
}

// Round 12
// 666.336 us; speedup vs baseline: 6.0748x; 6.0748x over previous
//
#include <hip/hip_runtime.h>
#include <hip/hip_bf16.h>
#include <math.h>

#define Bq 64
#define Sq 300
#define NH 4
#define DHd 32
#define Dd 128
#define NL 8
#define FF 512
#define NIN 36
#define SP 304   // padded seq for MFMA tiles
#define SPX 320  // j-range incl. last-tile overrun (10 tiles x 32)

typedef __attribute__((ext_vector_type(8))) short bf16x8;
typedef __attribute__((ext_vector_type(4))) float f32x4;

__device__ __forceinline__ float gelu_f(float x) {
    return 0.5f * x * (1.0f + erff(x * 0.70710678118654752f));
}
__device__ __forceinline__ bool bf16_mode(const unsigned* maskw) {
    return maskw[0] == 0x3F803F80u;   // two bf16 1.0s; f32 1.0 is 0x3F800000
}

// -------- dtype-agnostic input widening: all 36 inputs -> fp32 shadow in ws --------
struct ConvArgs {
    const void* src[NIN];
    float* dst[NIN];
    int n[NIN];
};

__global__ void convert_kernel(ConvArgs a, const unsigned* maskw) {
    bool bfm = bf16_mode(maskw);
    int bi = blockIdx.y;
    int n = a.n[bi];
    float* dst = a.dst[bi];
    int stride = gridDim.x * blockDim.x;
    int i0 = blockIdx.x * blockDim.x + threadIdx.x;
    if (bfm) {
        const __hip_bfloat16* s = (const __hip_bfloat16*)a.src[bi];
        for (int i = i0; i < n; i += stride) dst[i] = __bfloat162float(s[i]);
    } else {
        const float* s = (const float*)a.src[bi];
        for (int i = i0; i < n; i += stride) dst[i] = s[i];
    }
}

// -------- pack weights to MFMA B-operand layout [nt][kt][64][8] bf16 --------
__global__ void pack_kernel(const float* __restrict__ W1all, const float* __restrict__ W2all,
                            const float* __restrict__ Wqall, const float* __restrict__ Woall,
                            const float* __restrict__ Wr1, const float* __restrict__ Wr2,
                            const float* __restrict__ We2, const float* __restrict__ We3,
                            __hip_bfloat16* __restrict__ P1, __hip_bfloat16* __restrict__ P2,
                            __hip_bfloat16* __restrict__ Pq, __hip_bfloat16* __restrict__ Po,
                            __hip_bfloat16* __restrict__ Pr1, __hip_bfloat16* __restrict__ Pr2,
                            __hip_bfloat16* __restrict__ Pe2, __hip_bfloat16* __restrict__ Pe3) {
    int l = blockIdx.y;
    int which = blockIdx.z;
    if (which >= 4 && l != 0) return;
    int K = (which == 1) ? 512 : ((which == 6) ? 64 : 128);
    int N = (which == 0) ? 512 : (which == 1 ? 128 : (which == 2 ? 384 : (which == 5 ? 64 : 128)));
    int slots = (K / 32) * (N / 16) * 64;
    int idx = blockIdx.x * 256 + threadIdx.x;
    if (idx >= slots) return;
    int lane = idx & 63;
    int nkt = K / 32;
    int kt = (idx >> 6) % nkt;
    int nt = (idx >> 6) / nkt;
    const float* W; __hip_bfloat16* P;
    switch (which) {
        case 0:  W = W1all + (size_t)l * 128 * 512; P = P1 + (size_t)l * 65536; break;
        case 1:  W = W2all + (size_t)l * 512 * 128; P = P2 + (size_t)l * 65536; break;
        case 2:  W = Wqall + (size_t)l * 128 * 384; P = Pq + (size_t)l * 49152; break;
        case 3:  W = Woall + (size_t)l * 128 * 128; P = Po + (size_t)l * 16384; break;
        case 4:  W = Wr1; P = Pr1; break;
        case 5:  W = Wr2; P = Pr2; break;
        case 6:  W = We2; P = Pe2; break;
        default: W = We3; P = Pe3; break;
    }
    P += (size_t)idx * 8;
    int n = nt * 16 + (lane & 15);
    int k0 = kt * 32 + (lane >> 4) * 8;
    #pragma unroll
    for (int j = 0; j < 8; j++) P[j] = __float2bfloat16(W[(size_t)(k0 + j) * N + n]);
}

// -------- embedding v3: MFMA for layers 2&3, fp32 layer1 --------
__global__ __launch_bounds__(256) void embed_mfma_kernel(
        const float* __restrict__ inp, const float* __restrict__ mask,
        const float* __restrict__ W1, const float* __restrict__ b1,
        const __hip_bfloat16* __restrict__ Pe2, const float* __restrict__ b2,
        const __hip_bfloat16* __restrict__ Pe3, const float* __restrict__ b3,
        const float* __restrict__ tok_emb,
        const float* __restrict__ ln_s, const float* __restrict__ ln_b,
        float* __restrict__ x) {
    int blk = blockIdx.x;       // 0..1199
    int t = threadIdx.x;        // 0..255
    int w = t >> 6, lane = t & 63;
    int row0 = blk * 16;
    __shared__ float f[16][4];
    __shared__ __align__(16) __hip_bfloat16 e1a[16 * 72];
    __shared__ __align__(16) __hip_bfloat16 e2a[16 * 136];
    __shared__ float dbuf[16 * 132];
    if (t < 64) f[t >> 2][t & 3] = inp[(size_t)(row0 + (t >> 2)) * 4 + (t & 3)];
    __syncthreads();
    {
        int r1 = t >> 4, n0 = (t & 15) * 4;
        float f0 = f[r1][0], f1 = f[r1][1], f2 = f[r1][2];
        #pragma unroll
        for (int j = 0; j < 4; j++) {
            int n = n0 + j;
            float a = b1[n] + f0 * W1[n] + f1 * W1[64 + n] + f2 * W1[128 + n];
            e1a[r1 * 72 + n] = __float2bfloat16(gelu_f(a));
        }
    }
    __syncthreads();
    int m = lane & 15, quad = lane >> 4;
    bf16x8 a2[2];
    #pragma unroll
    for (int kt = 0; kt < 2; kt++) a2[kt] = *(bf16x8*)&e1a[m * 72 + kt * 32 + quad * 8];
    #pragma unroll
    for (int nt0 = 0; nt0 < 2; nt0++) {
        int nt = w * 2 + nt0;
        f32x4 acc = {0.f, 0.f, 0.f, 0.f};
        const bf16x8* bp = (const bf16x8*)(Pe2 + (size_t)nt * 2 * 512);
        #pragma unroll
        for (int kt = 0; kt < 2; kt++) {
            bf16x8 bfr = bp[kt * 64 + lane];
            acc = __builtin_amdgcn_mfma_f32_16x16x32_bf16(a2[kt], bfr, acc, 0, 0, 0);
        }
        int n = nt * 16 + m;
        float bb = b2[n];
        #pragma unroll
        for (int r = 0; r < 4; r++)
            e2a[(quad * 4 + r) * 136 + n] = __float2bfloat16(gelu_f(acc[r] + bb));
    }
    __syncthreads();
    bf16x8 a3[4];
    #pragma unroll
    for (int kt = 0; kt < 4; kt++) a3[kt] = *(bf16x8*)&e2a[m * 136 + kt * 32 + quad * 8];
    f32x4 acc2[2] = {{0.f,0.f,0.f,0.f}, {0.f,0.f,0.f,0.f}};
    #pragma unroll
    for (int kt = 0; kt < 4; kt++) {
        #pragma unroll
        for (int nt0 = 0; nt0 < 2; nt0++) {
            int nt = w * 2 + nt0;
            bf16x8 bfr = ((const bf16x8*)(Pe3 + (size_t)nt * 4 * 512))[kt * 64 + lane];
            acc2[nt0] = __builtin_amdgcn_mfma_f32_16x16x32_bf16(a3[kt], bfr, acc2[nt0], 0, 0, 0);
        }
    }
    #pragma unroll
    for (int nt0 = 0; nt0 < 2; nt0++) {
        int n = (w * 2 + nt0) * 16 + m;
        float bb = b3[n];
        #pragma unroll
        for (int r = 0; r < 4; r++) {
            int row = quad * 4 + r;
            int tok = (int)f[row][3];
            dbuf[row * 132 + n] = gelu_f(acc2[nt0][r] + bb) + tok_emb[tok * 128 + n];
        }
    }
    __syncthreads();
    #pragma unroll
    for (int rr = 0; rr < 4; rr++) {
        int row = w * 4 + rr;
        int c0 = lane, c1 = lane + 64;
        float y0 = dbuf[row * 132 + c0];
        float y1 = dbuf[row * 132 + c1];
        float sm = y0 + y1;
        #pragma unroll
        for (int o = 32; o > 0; o >>= 1) sm += __shfl_xor(sm, o);
        float mu = sm * (1.0f / 128.0f);
        float d0 = y0 - mu, d1 = y1 - mu;
        float vv = d0 * d0 + d1 * d1;
        #pragma unroll
        for (int o = 32; o > 0; o >>= 1) vv += __shfl_xor(vv, o);
        float rstd = rsqrtf(vv * (1.0f / 128.0f) + 1e-7f);
        float mk = mask[row0 + row];
        x[(size_t)(row0 + row) * 128 + c0] = (d0 * rstd * ln_s[c0] + ln_b[c0]) * mk;
        x[(size_t)(row0 + row) * 128 + c1] = (d1 * rstd * ln_s[c1] + ln_b[c1]) * mk;
    }
}

// -------- qkv standalone (layer 0 only): 32 rows/block, 512 thr --------
__global__ __launch_bounds__(512) void qkv_mfma_kernel(const float* __restrict__ x,
                                                       const __hip_bfloat16* __restrict__ Pq,
                                                       const float* __restrict__ qb, const float* __restrict__ vb,
                                                       __hip_bfloat16* __restrict__ qbf,
                                                       __hip_bfloat16* __restrict__ kbf,
                                                       __hip_bfloat16* __restrict__ vT) {
    int blk = blockIdx.x;       // 0..599
    int t = threadIdx.x;        // 0..511
    int w = t >> 6, lane = t & 63;
    int row0 = blk * 32;
    __shared__ __align__(16) __hip_bfloat16 xa[32 * 136];
    for (int i = t; i < 1024; i += 512) {
        float4 v4 = ((const float4*)(x + (size_t)row0 * 128))[i];
        int r = i >> 5, c4 = (i & 31) * 4;
        __hip_bfloat16* d = &xa[r * 136 + c4];
        d[0] = __float2bfloat16(v4.x); d[1] = __float2bfloat16(v4.y);
        d[2] = __float2bfloat16(v4.z); d[3] = __float2bfloat16(v4.w);
    }
    __syncthreads();
    int m = lane & 15, quad = lane >> 4;
    bf16x8 a1[2][4];
    #pragma unroll
    for (int mt = 0; mt < 2; mt++)
        #pragma unroll
        for (int kt = 0; kt < 4; kt++)
            a1[mt][kt] = *(bf16x8*)&xa[(mt * 16 + m) * 136 + kt * 32 + quad * 8];
    const float inv_scale = 0.10206207261596576f;  // 1/sqrt(96)
    #pragma unroll
    for (int nt0 = 0; nt0 < 3; nt0++) {
        int nt = w * 3 + nt0;
        f32x4 acc[2] = {{0.f,0.f,0.f,0.f}, {0.f,0.f,0.f,0.f}};
        const bf16x8* bp = (const bf16x8*)(Pq + (size_t)nt * 4 * 512);
        #pragma unroll
        for (int kt = 0; kt < 4; kt++) {
            bf16x8 bfr = bp[kt * 64 + lane];
            #pragma unroll
            for (int mt = 0; mt < 2; mt++)
                acc[mt] = __builtin_amdgcn_mfma_f32_16x16x32_bf16(a1[mt][kt], bfr, acc[mt], 0, 0, 0);
        }
        int n = nt * 16 + m;
        int h = n / 96, mm = (n % 96) / 32, d = n % 32;
        float qbv = qb[h * 32 + d], vbv = vb[h * 32 + d];
        #pragma unroll
        for (int mt = 0; mt < 2; mt++) {
            #pragma unroll
            for (int r = 0; r < 4; r++) {
                int row = row0 + mt * 16 + quad * 4 + r;
                int bb = row / Sq, s = row % Sq;
                int bh = bb * NH + h;
                float a = acc[mt][r];
                if (mm == 0) {
                    qbf[((size_t)bh * SP + s) * 32 + d] = __float2bfloat16((a + qbv) * inv_scale);
                } else if (mm == 1) {
                    kbf[((size_t)bh * SP + s) * 32 + d] = __float2bfloat16(a);
                } else {
                    vT[((size_t)bh * 32 + d) * SP + s] = __float2bfloat16(a + vbv);
                }
            }
        }
    }
}

// -------- zero the never-written padding rows/cols (once, before layer loop) --------
__global__ void pad_kernel(__hip_bfloat16* qbf, __hip_bfloat16* kbf, __hip_bfloat16* vT) {
    int i = blockIdx.x * 256 + threadIdx.x;   // 256 bh * 4 s * 32 d = 32768
    if (i >= 256 * 4 * 32) return;
    int bh = i >> 7, s = Sq + ((i >> 5) & 3), d = i & 31;
    __hip_bfloat16 z = __float2bfloat16(0.0f);
    qbf[((size_t)bh * SP + s) * 32 + d] = z;
    kbf[((size_t)bh * SP + s) * 32 + d] = z;
    vT[((size_t)bh * 32 + d) * SP + s] = z;
}

// -------- positional projections -> bf16 MFMA-B layout [L][NH][16 r][32 d] --------
__global__ void pos_kernel(const float* __restrict__ rel_emb,
                           const float* __restrict__ pkW_all, const float* __restrict__ pqW_all,
                           const float* __restrict__ pqb_all,
                           __hip_bfloat16* __restrict__ poskb, __hip_bfloat16* __restrict__ posqb) {
    int l = blockIdx.y;         // 0..NL-1
    int bi = blockIdx.x;        // 0..31
    int which = bi >> 4;        // 0: posk, 1: posq
    int r = bi & 15;
    int t = threadIdx.x;        // 0..127 = h*32+d
    __shared__ float re[128];
    re[t] = rel_emb[r * 128 + t];
    __syncthreads();
    const float* W = (which ? pqW_all : pkW_all) + (size_t)l * 128 * 128;
    float a = 0.0f;
    for (int k = 0; k < 128; k++) a += re[k] * W[k * 128 + t];
    int h = t >> 5, d = t & 31;
    size_t o = ((size_t)(l * NH + h) * 16 + r) * 32 + d;
    if (which) { a = (a + pqb_all[l * 128 + t]) * 0.10206207261596576f; posqb[o] = __float2bfloat16(a); }
    else       { poskb[o] = __float2bfloat16(a); }
}

// -------- MFMA attention v2: swapped QK^T, in-kernel c2p/p2c, mask fold; ctx bf16 out --------
__global__ __launch_bounds__(256) void attn_mfma_kernel(const __hip_bfloat16* __restrict__ qbf,
                                                        const __hip_bfloat16* __restrict__ kbf,
                                                        const __hip_bfloat16* __restrict__ vT,
                                                        const __hip_bfloat16* __restrict__ poskb,
                                                        const __hip_bfloat16* __restrict__ posqb,
                                                        const float* __restrict__ mask,
                                                        __hip_bfloat16* __restrict__ ctxb) {
    int bh = blockIdx.x;            // 0..255
    int b = bh >> 2, h = bh & 3;
    int t = threadIdx.x;
    int w = t >> 6, lane = t & 63;
    int m = lane & 15, quad = lane >> 4;

    __shared__ float p2cS[SPX * 17];                        // 21760 B, block-shared
    __shared__ float c2pS[4][16 * 17];                      // per-wave
    __shared__ __align__(16) __hip_bfloat16 pT[4][16 * 40]; // per-wave P, [q][j] layout

    // ---- stage p2cS[j][r] = k[j].posq[r] via MFMA, with mask/padding folded to -3e4 ----
    {
        bf16x8 pqf = *(const bf16x8*)&posqb[(h * 16 + m) * 32 + quad * 8];
        #pragma unroll
        for (int it = 0; it < 5; it++) {
            int jb = (w + it * 4) * 16;
            bf16x8 kf2 = *(const bf16x8*)&kbf[((size_t)bh * SP + jb + m) * 32 + quad * 8];
            f32x4 pc = __builtin_amdgcn_mfma_f32_16x16x32_bf16(kf2, pqf, (f32x4){0.f,0.f,0.f,0.f}, 0, 0, 0);
            #pragma unroll
            for (int r = 0; r < 4; r++) {
                int j = jb + quad * 4 + r;                  // D row = A(K) row
                float mv = (j < Sq) ? mask[b * Sq + j] : 0.0f;
                p2cS[j * 17 + m] = (mv > 0.0f) ? pc[r] : -30000.0f;
            }
        }
    }
    __syncthreads();

    int qt = blockIdx.y * 4 + w;    // 0..19
    if (qt >= 19) return;           // no barriers after this point
    int q0 = qt * 16;

    float* c2pW = c2pS[w];
    __hip_bfloat16* pTW = pT[w];

    bf16x8 aq = *(const bf16x8*)&qbf[((size_t)bh * SP + q0 + m) * 32 + quad * 8];

    // ---- c2pW[q][r] = q[q].posk[r] via one MFMA (wave-private) ----
    {
        bf16x8 pkf = *(const bf16x8*)&poskb[(h * 16 + m) * 32 + quad * 8];
        f32x4 cc = __builtin_amdgcn_mfma_f32_16x16x32_bf16(aq, pkf, (f32x4){0.f,0.f,0.f,0.f}, 0, 0, 0);
        #pragma unroll
        for (int r = 0; r < 4; r++) c2pW[(quad * 4 + r) * 17 + m] = cc[r];
    }

    int qi = q0 + m;                // this lane's q-row (swapped layout)
    f32x4 oacc[2] = {{0.f,0.f,0.f,0.f}, {0.f,0.f,0.f,0.f}};
    float lacc = 0.0f;

    for (int jt2 = 0; jt2 < 10; jt2++) {
        int j0 = jt2 * 32;
        #pragma unroll
        for (int half = 0; half < 2; half++) {
            int jh = j0 + half * 16;
            bf16x8 kf = *(const bf16x8*)&kbf[((size_t)bh * SP + jh + m) * 32 + quad * 8];
            f32x4 sc = __builtin_amdgcn_mfma_f32_16x16x32_bf16(kf, aq, (f32x4){0.f,0.f,0.f,0.f}, 0, 0, 0);
            int jb2 = jh + quad * 4;
            int base = qi - jb2 + 8;
            __hip_bfloat16 pb[4];
            #pragma unroll
            for (int r = 0; r < 4; r++) {
                int rr = base - r; rr = rr < 0 ? 0 : (rr > 15 ? 15 : rr);
                float sv = sc[r] + c2pW[m * 17 + rr] + p2cS[(jb2 + r) * 17 + rr];
                float p = __expf(sv);
                lacc += p;
                pb[r] = __float2bfloat16(p);
            }
            *(uint2*)&pTW[m * 40 + half * 16 + quad * 4] = *(uint2*)pb;   // packed 4x bf16
        }
        bf16x8 ap = *(bf16x8*)&pTW[m * 40 + quad * 8];
        #pragma unroll
        for (int nt = 0; nt < 2; nt++) {
            bf16x8 vf = *(const bf16x8*)&vT[((size_t)bh * 32 + nt * 16 + m) * SP + j0 + quad * 8];
            oacc[nt] = __builtin_amdgcn_mfma_f32_16x16x32_bf16(ap, vf, oacc[nt], 0, 0, 0);
        }
    }

    lacc += __shfl_xor(lacc, 16);
    lacc += __shfl_xor(lacc, 32);
    #pragma unroll
    for (int r = 0; r < 4; r++) {
        int qrow = quad * 4 + r;
        float lr = __shfl(lacc, qrow);
        int qi2 = q0 + qrow;
        float qm = (qi2 < Sq) ? mask[b * Sq + qi2] : 0.0f;
        float inv = (qm > 0.0f && lr > 0.0f) ? 1.0f / lr : 0.0f;
        if (qi2 < Sq) {
            size_t base2 = ((size_t)(b * Sq + qi2)) * 128 + h * 32;
            ctxb[base2 + m]      = __float2bfloat16(oacc[0][r] * inv);
            ctxb[base2 + 16 + m] = __float2bfloat16(oacc[1][r] * inv);
        }
    }
}

// -------- FUSED attn_out + FFN + next-layer qkv: 16 rows/block, 256 thr --------
__global__ __launch_bounds__(256) void aoffn_mfma_kernel(
        const __hip_bfloat16* __restrict__ ctxb,
        const __hip_bfloat16* __restrict__ Po, const float* __restrict__ ob,
        const float* __restrict__ ln1s, const float* __restrict__ ln1b,
        const __hip_bfloat16* __restrict__ P1, const float* __restrict__ b1,
        const __hip_bfloat16* __restrict__ P2, const float* __restrict__ b2,
        const float* __restrict__ ln2s, const float* __restrict__ ln2b,
        float* __restrict__ x,
        int do_qkv,
        const __hip_bfloat16* __restrict__ Pqn,
        const float* __restrict__ qbn, const float* __restrict__ vbn,
        __hip_bfloat16* __restrict__ qbf, __hip_bfloat16* __restrict__ kbf,
        __hip_bfloat16* __restrict__ vT) {
    int blk = blockIdx.x;       // 0..1199
    int t = threadIdx.x;        // 0..255
    int w = t >> 6, lane = t & 63;
    int row0 = blk * 16;

    __shared__ __align__(16) __hip_bfloat16 ca[16 * 136];   // ctx, then x1, then x2 (A-layout)
    __shared__ __align__(16) char hbuf[16 * 520 * 2];       // ha(bf16) / dbuf(f32) union
    __hip_bfloat16* ha = (__hip_bfloat16*)hbuf;             // [16][520]
    float* dbuf = (float*)hbuf;                             // [16][132]

    {   // stage ctx (bf16 direct): 16*128 bf16 = 256 thr x 8
        uint4 cv = ((const uint4*)(ctxb + (size_t)row0 * 128))[t];
        int r = t >> 4, c8 = (t & 15) * 8;
        *(uint4*)&ca[r * 136 + c8] = cv;
    }
    __syncthreads();

    int m = lane & 15, quad = lane >> 4;

    // ---- attn_out matmul: K=128, N=128; 2 nt/wave ----
    {
        bf16x8 a1[4];
        #pragma unroll
        for (int kt = 0; kt < 4; kt++) a1[kt] = *(bf16x8*)&ca[m * 136 + kt * 32 + quad * 8];
        f32x4 acc2[2] = {{0.f,0.f,0.f,0.f}, {0.f,0.f,0.f,0.f}};
        #pragma unroll
        for (int kt = 0; kt < 4; kt++) {
            #pragma unroll
            for (int nt0 = 0; nt0 < 2; nt0++) {
                int nt = w * 2 + nt0;
                bf16x8 bfr = ((const bf16x8*)(Po + (size_t)nt * 4 * 512))[kt * 64 + lane];
                acc2[nt0] = __builtin_amdgcn_mfma_f32_16x16x32_bf16(a1[kt], bfr, acc2[nt0], 0, 0, 0);
            }
        }
        #pragma unroll
        for (int nt0 = 0; nt0 < 2; nt0++) {
            int n = (w * 2 + nt0) * 16 + m;
            #pragma unroll
            for (int r = 0; r < 4; r++) dbuf[(quad * 4 + r) * 132 + n] = acc2[nt0][r];
        }
    }
    __syncthreads();

    // ---- LN1 (+residual, x read from global) -> registers + ca (bf16) ----
    float x1a[4], x1b[4];
    #pragma unroll
    for (int rr = 0; rr < 4; rr++) {
        int row = w * 4 + rr;       // 4 waves x 4 = 16 rows
        int c0 = lane, c1 = lane + 64;
        size_t g = (size_t)(row0 + row) * 128;
        float y0 = dbuf[row * 132 + c0] + ob[c0] + x[g + c0];
        float y1 = dbuf[row * 132 + c1] + ob[c1] + x[g + c1];
        float sm = y0 + y1;
        #pragma unroll
        for (int o = 32; o > 0; o >>= 1) sm += __shfl_xor(sm, o);
        float mu = sm * (1.0f / 128.0f);
        float d0 = y0 - mu, d1 = y1 - mu;
        float vv = d0 * d0 + d1 * d1;
        #pragma unroll
        for (int o = 32; o > 0; o >>= 1) vv += __shfl_xor(vv, o);
        float rstd = rsqrtf(vv * (1.0f / 128.0f) + 1e-7f);
        float o0 = d0 * rstd * ln1s[c0] + ln1b[c0];
        float o1 = d1 * rstd * ln1s[c1] + ln1b[c1];
        x1a[rr] = o0;
        x1b[rr] = o1;
        ca[row * 136 + c0] = __float2bfloat16(o0);
        ca[row * 136 + c1] = __float2bfloat16(o1);
    }
    __syncthreads();

    // ---- FFN phase 1: h = gelu(x1 @ W1 + b1); N=512, 8 nt/wave ----
    {
        bf16x8 a1[4];
        #pragma unroll
        for (int kt = 0; kt < 4; kt++)
            a1[kt] = *(bf16x8*)&ca[m * 136 + kt * 32 + quad * 8];
        #pragma unroll
        for (int nt0 = 0; nt0 < 8; nt0++) {
            int nt = w * 8 + nt0;
            f32x4 acc = {0.f, 0.f, 0.f, 0.f};
            const bf16x8* bp = (const bf16x8*)(P1 + (size_t)nt * 4 * 512);
            #pragma unroll
            for (int kt = 0; kt < 4; kt++) {
                bf16x8 bfr = bp[kt * 64 + lane];
                acc = __builtin_amdgcn_mfma_f32_16x16x32_bf16(a1[kt], bfr, acc, 0, 0, 0);
            }
            int n = nt * 16 + m;
            float bb = b1[n];
            #pragma unroll
            for (int r = 0; r < 4; r++)
                ha[(quad * 4 + r) * 520 + n] = __float2bfloat16(gelu_f(acc[r] + bb));
        }
    }
    __syncthreads();

    // ---- FFN phase 2: K=512 (16 kt), N=128 (2 nt/wave) ----
    f32x4 acc2[2] = {{0.f,0.f,0.f,0.f}, {0.f,0.f,0.f,0.f}};
    #pragma unroll
    for (int kt = 0; kt < 16; kt++) {
        bf16x8 a = *(bf16x8*)&ha[m * 520 + kt * 32 + quad * 8];
        #pragma unroll
        for (int nt0 = 0; nt0 < 2; nt0++) {
            int nt = w * 2 + nt0;
            bf16x8 bfr = ((const bf16x8*)(P2 + (size_t)nt * 16 * 512))[kt * 64 + lane];
            acc2[nt0] = __builtin_amdgcn_mfma_f32_16x16x32_bf16(a, bfr, acc2[nt0], 0, 0, 0);
        }
    }
    __syncthreads();            // all waves done READING ha; dbuf may overwrite
    #pragma unroll
    for (int nt0 = 0; nt0 < 2; nt0++) {
        int n = (w * 2 + nt0) * 16 + m;
        #pragma unroll
        for (int r = 0; r < 4; r++)
            dbuf[(quad * 4 + r) * 132 + n] = acc2[nt0][r];
    }
    __syncthreads();

    // ---- LN2 (+residual x1 from registers) -> x global, and x2 bf16 into ca ----
    #pragma unroll
    for (int rr = 0; rr < 4; rr++) {
        int row = w * 4 + rr;
        int c0 = lane, c1 = lane + 64;
        float y0 = dbuf[row * 132 + c0] + b2[c0] + x1a[rr];
        float y1 = dbuf[row * 132 + c1] + b2[c1] + x1b[rr];
        float sm = y0 + y1;
        #pragma unroll
        for (int o = 32; o > 0; o >>= 1) sm += __shfl_xor(sm, o);
        float mu = sm * (1.0f / 128.0f);
        float d0 = y0 - mu, d1 = y1 - mu;
        float vv = d0 * d0 + d1 * d1;
        #pragma unroll
        for (int o = 32; o > 0; o >>= 1) vv += __shfl_xor(vv, o);
        float rstd = rsqrtf(vv * (1.0f / 128.0f) + 1e-7f);
        float o0 = d0 * rstd * ln2s[c0] + ln2b[c0];
        float o1 = d1 * rstd * ln2s[c1] + ln2b[c1];
        x[(size_t)(row0 + row) * 128 + c0] = o0;
        x[(size_t)(row0 + row) * 128 + c1] = o1;
        ca[row * 136 + c0] = __float2bfloat16(o0);
        ca[row * 136 + c1] = __float2bfloat16(o1);
    }
    if (!do_qkv) return;
    __syncthreads();

    // ---- next-layer qkv: K=128, N=384; 6 nt/wave ----
    {
        bf16x8 aq[4];
        #pragma unroll
        for (int kt = 0; kt < 4; kt++) aq[kt] = *(bf16x8*)&ca[m * 136 + kt * 32 + quad * 8];
        const float inv_scale = 0.10206207261596576f;  // 1/sqrt(96)
        #pragma unroll
        for (int nt0 = 0; nt0 < 6; nt0++) {
            int nt = w * 6 + nt0;
            f32x4 acc = {0.f, 0.f, 0.f, 0.f};
            const bf16x8* bp = (const bf16x8*)(Pqn + (size_t)nt * 4 * 512);
            #pragma unroll
            for (int kt = 0; kt < 4; kt++) {
                bf16x8 bfr = bp[kt * 64 + lane];
                acc = __builtin_amdgcn_mfma_f32_16x16x32_bf16(aq[kt], bfr, acc, 0, 0, 0);
            }
            int n = nt * 16 + m;
            int h = n / 96, mm = (n % 96) / 32, d = n % 32;
            float qbv = qbn[h * 32 + d], vbv = vbn[h * 32 + d];
            #pragma unroll
            for (int r = 0; r < 4; r++) {
                int row = row0 + quad * 4 + r;
                int bb = row / Sq, s = row % Sq;
                int bh = bb * NH + h;
                float a = acc[r];
                if (mm == 0) {
                    qbf[((size_t)bh * SP + s) * 32 + d] = __float2bfloat16((a + qbv) * inv_scale);
                } else if (mm == 1) {
                    kbf[((size_t)bh * SP + s) * 32 + d] = __float2bfloat16(a);
                } else {
                    vT[((size_t)bh * 32 + d) * SP + s] = __float2bfloat16(a + vbv);
                }
            }
        }
    }
}

// -------- reconstruction MLP via MFMA: 16 rows/block; 128->128->64->5 --------
__global__ __launch_bounds__(256) void rec_mfma_kernel(const float* __restrict__ x,
                                                       const __hip_bfloat16* __restrict__ Pr1,
                                                       const float* __restrict__ b1,
                                                       const __hip_bfloat16* __restrict__ Pr2,
                                                       const float* __restrict__ b2,
                                                       const float* __restrict__ W3, const float* __restrict__ b3,
                                                       float* __restrict__ r3) {
    int blk = blockIdx.x;       // 0..1199
    int t = threadIdx.x;        // 0..255
    int w = t >> 6, lane = t & 63;
    int row0 = blk * 16;
    __shared__ __align__(16) __hip_bfloat16 xa[16 * 136];
    __shared__ __align__(16) __hip_bfloat16 ha[16 * 136];
    __shared__ float r2s[16 * 68];
    for (int i = t; i < 512; i += 256) {
        float4 v4 = ((const float4*)(x + (size_t)row0 * 128))[i];
        int r = i >> 5, c4 = (i & 31) * 4;
        __hip_bfloat16* d = &xa[r * 136 + c4];
        d[0] = __float2bfloat16(v4.x); d[1] = __float2bfloat16(v4.y);
        d[2] = __float2bfloat16(v4.z); d[3] = __float2bfloat16(v4.w);
    }
    __syncthreads();
    int m = lane & 15, quad = lane >> 4;

    bf16x8 a1[4];
    #pragma unroll
    for (int kt = 0; kt < 4; kt++) a1[kt] = *(bf16x8*)&xa[m * 136 + kt * 32 + quad * 8];
    #pragma unroll
    for (int nt0 = 0; nt0 < 2; nt0++) {
        int nt = w * 2 + nt0;
        f32x4 acc = {0.f, 0.f, 0.f, 0.f};
        const bf16x8* bp = (const bf16x8*)(Pr1 + (size_t)nt * 4 * 512);
        #pragma unroll
        for (int kt = 0; kt < 4; kt++) {
            bf16x8 bfr = bp[kt * 64 + lane];
            acc = __builtin_amdgcn_mfma_f32_16x16x32_bf16(a1[kt], bfr, acc, 0, 0, 0);
        }
        int n = nt * 16 + m;
        float bb = b1[n];
        #pragma unroll
        for (int r = 0; r < 4; r++)
            ha[(quad * 4 + r) * 136 + n] = __float2bfloat16(gelu_f(acc[r] + bb));
    }
    __syncthreads();

    {
        f32x4 acc = {0.f, 0.f, 0.f, 0.f};
        const bf16x8* bp = (const bf16x8*)(Pr2 + (size_t)w * 4 * 512);
        #pragma unroll
        for (int kt = 0; kt < 4; kt++) {
            bf16x8 a = *(bf16x8*)&ha[m * 136 + kt * 32 + quad * 8];
            bf16x8 bfr = bp[kt * 64 + lane];
            acc = __builtin_amdgcn_mfma_f32_16x16x32_bf16(a, bfr, acc, 0, 0, 0);
        }
        int n = w * 16 + m;
        float bb = b2[n];
        #pragma unroll
        for (int r = 0; r < 4; r++)
            r2s[(quad * 4 + r) * 68 + n] = gelu_f(acc[r] + bb);
    }
    __syncthreads();

    if (t < 80) {
        int row = t / 5, c = t % 5;
        float a = b3[c];
        for (int k = 0; k < 64; k++) a += r2s[row * 68 + k] * W3[k * 5 + c];
        r3[(size_t)(row0 + row) * 5 + c] = gelu_f(a);
    }
}

// -------- connection head v2 (R15 win, unchanged) --------
__global__ void conn_kernel(const float* __restrict__ r3, const float* __restrict__ W,
                            const float* __restrict__ b, void* out, const unsigned* maskw) {
    bool bfm = bf16_mode(maskw);
    int cb = blockIdx.x;     // 0..39
    int bg = blockIdx.y;     // 0..15
    int t = threadIdx.x;     // 0..255
    int cl = t & 63;
    int kq = t >> 6;
    int col = cb * 64 + cl;
    __shared__ float rs[4 * 1500];
    __shared__ float pacc[4 * 64 * 4];
    {
        const float4* src = (const float4*)(r3 + (size_t)bg * 4 * 1500);
        for (int i = t; i < 1500; i += 256) ((float4*)rs)[i] = src[i];
    }
    __syncthreads();
    float acc[4] = {0.f, 0.f, 0.f, 0.f};
    if (col < 2500) {
        for (int k = kq * 4; k < 1500; k += 16) {
            float w0 = W[(size_t)(k + 0) * 2500 + col];
            float w1 = W[(size_t)(k + 1) * 2500 + col];
            float w2 = W[(size_t)(k + 2) * 2500 + col];
            float w3 = W[(size_t)(k + 3) * 2500 + col];
            #pragma unroll
            for (int bb = 0; bb < 4; bb++) {
                float4 rv = *(const float4*)&rs[bb * 1500 + k];
                acc[bb] += rv.x * w0 + rv.y * w1 + rv.z * w2 + rv.w * w3;
            }
        }
    }
    #pragma unroll
    for (int bb = 0; bb < 4; bb++) pacc[(kq * 64 + cl) * 4 + bb] = acc[bb];
    __syncthreads();
    if (kq == 0 && col < 2500) {
        float bv = b[col];
        #pragma unroll
        for (int bb = 0; bb < 4; bb++) {
            float a = bv + pacc[(0 * 64 + cl) * 4 + bb] + pacc[(1 * 64 + cl) * 4 + bb]
                         + pacc[(2 * 64 + cl) * 4 + bb] + pacc[(3 * 64 + cl) * 4 + bb];
            int ob = bg * 4 + bb;
            if (bfm) ((__hip_bfloat16*)out)[(size_t)ob * 2500 + col] = __float2bfloat16(a);
            else     ((float*)out)[(size_t)ob * 2500 + col] = a;
        }
    }
}

extern "C" void kernel_launch(void* const* d_in, const int* in_sizes, int n_in,
                              void* d_out, int out_size, void* d_ws, size_t ws_size,
                              hipStream_t stream) {
    float* ws = (float*)d_ws;

    float* cv[NIN];
    size_t off = 0;
    for (int i = 0; i < NIN; i++) { cv[i] = ws + off; off += (size_t)in_sizes[i]; }

    const float* inp      = cv[0];
    const float* mask     = cv[1];
    const float* emb_W1   = cv[2];
    const float* emb_b1   = cv[3];
    const float* emb_W2   = cv[4];
    const float* emb_b2   = cv[5];
    const float* emb_W3   = cv[6];
    const float* emb_b3   = cv[7];
    const float* tok_emb  = cv[8];
    const float* emb_ln_s = cv[9];
    const float* emb_ln_b = cv[10];
    const float* rel_emb  = cv[11];
    const float* qkv_W    = cv[12];
    const float* q_bias   = cv[13];
    const float* v_bias   = cv[14];
    const float* pos_k_W  = cv[15];
    const float* pos_q_W  = cv[16];
    const float* pos_q_b  = cv[17];
    const float* attn_out_W = cv[18];
    const float* attn_out_b = cv[19];
    const float* ln1_s    = cv[20];
    const float* ln1_b    = cv[21];
    const float* ffn_W1   = cv[22];
    const float* ffn_b1   = cv[23];
    const float* ffn_W2   = cv[24];
    const float* ffn_b2   = cv[25];
    const float* ln2_s    = cv[26];
    const float* ln2_b    = cv[27];
    const float* rec_W1   = cv[28];
    const float* rec_b1   = cv[29];
    const float* rec_W2   = cv[30];
    const float* rec_b2   = cv[31];
    const float* rec_W3   = cv[32];
    const float* rec_b3   = cv[33];
    const float* conn_W   = cv[34];
    const float* conn_b   = cv[35];

    const int NTOK = Bq * Sq;            // 19200
    float* x    = ws + off;
    float* q    = x    + (size_t)NTOK * 128;             // (unused, kept for layout)
    float* k    = q    + (size_t)Bq * NH * Sq * 32;      // (unused)
    float* ctx  = k    + (size_t)Bq * NH * Sq * 32;      // reused as bf16 ctx
    float* c2p  = ctx  + (size_t)NTOK * 128;             // (unused)
    float* p2c  = c2p  + (size_t)Bq * NH * Sq * 16;      // (unused)
    float* posk = p2c  + (size_t)Bq * NH * Sq * 16;      // (unused)
    float* posq = posk + (size_t)NL * 16 * 128;          // (unused)
    float* r3b  = posq + (size_t)NL * 16 * 128;
    float* endf = r3b  + (size_t)NTOK * 5;
    __hip_bfloat16* P1 = (__hip_bfloat16*)endf;          // 8 x 65536 bf16
    __hip_bfloat16* P2 = P1 + (size_t)NL * 65536;
    __hip_bfloat16* Pq = P2 + (size_t)NL * 65536;        // 8 x 49152
    __hip_bfloat16* Po = Pq + (size_t)NL * 49152;        // 8 x 16384
    __hip_bfloat16* qbf = Po + (size_t)NL * 16384;       // 256*SP*32 each
    __hip_bfloat16* kbf = qbf + (size_t)256 * SP * 32;
    __hip_bfloat16* vTb = kbf + (size_t)256 * SP * 32;
    __hip_bfloat16* Pr1 = vTb + (size_t)256 * SP * 32;   // 16384
    __hip_bfloat16* Pr2 = Pr1 + 16384;                   // 8192
    __hip_bfloat16* Pe2 = Pr2 + 8192;                    // 8192
    __hip_bfloat16* Pe3 = Pe2 + 8192;                    // 16384
    __hip_bfloat16* Pkb = Pe3 + 16384;                   // [NL][NH][16][32] = 16384
    __hip_bfloat16* Pqb = Pkb + (size_t)NL * 2048;       // same
    __hip_bfloat16* ctxb = (__hip_bfloat16*)ctx;         // bf16 ctx [NTOK][128]

    const unsigned* maskw = (const unsigned*)d_in[1];

    ConvArgs ca;
    for (int i = 0; i < NIN; i++) {
        ca.src[i] = d_in[i];
        ca.dst[i] = cv[i];
        ca.n[i] = in_sizes[i];
    }
    convert_kernel<<<dim3(256, NIN), 256, 0, stream>>>(ca, maskw);
    pack_kernel<<<dim3(32, NL, 8), 256, 0, stream>>>(ffn_W1, ffn_W2, qkv_W, attn_out_W,
                                                     rec_W1, rec_W2, emb_W2, emb_W3,
                                                     P1, P2, Pq, Po, Pr1, Pr2, Pe2, Pe3);

    embed_mfma_kernel<<<NTOK / 16, 256, 0, stream>>>(inp, mask, emb_W1, emb_b1,
                                                     Pe2, emb_b2, Pe3, emb_b3,
                                                     tok_emb, emb_ln_s, emb_ln_b, x);

    pos_kernel<<<dim3(32, NL), 128, 0, stream>>>(rel_emb, pos_k_W, pos_q_W, pos_q_b, Pkb, Pqb);
    pad_kernel<<<128, 256, 0, stream>>>(qbf, kbf, vTb);

    // layer-0 qkv (standalone); layers 1..7 get qkv fused into the previous aoffn
    qkv_mfma_kernel<<<NTOK / 32, 512, 0, stream>>>(x, Pq, q_bias, v_bias, qbf, kbf, vTb);

    for (int l = 0; l < NL; l++) {
        attn_mfma_kernel<<<dim3(256, 5), 256, 0, stream>>>(qbf, kbf, vTb,
                                                           Pkb + (size_t)l * 2048,
                                                           Pqb + (size_t)l * 2048,
                                                           mask, ctxb);
        int ln = (l + 1 < NL) ? (l + 1) : 0;    // dummy (unused) when do_qkv=0
        aoffn_mfma_kernel<<<NTOK / 16, 256, 0, stream>>>(ctxb,
                                                         Po + (size_t)l * 16384, attn_out_b + l * 128,
                                                         ln1_s + l * 128, ln1_b + l * 128,
                                                         P1 + (size_t)l * 65536, ffn_b1 + l * 512,
                                                         P2 + (size_t)l * 65536, ffn_b2 + l * 128,
                                                         ln2_s + l * 128, ln2_b + l * 128, x,
                                                         (l + 1 < NL) ? 1 : 0,
                                                         Pq + (size_t)ln * 49152,
                                                         q_bias + ln * 128, v_bias + ln * 128,
                                                         qbf, kbf, vTb);
    }

    rec_mfma_kernel<<<NTOK / 16, 256, 0, stream>>>(x, Pr1, rec_b1, Pr2, rec_b2,
                                                   rec_W3, rec_b3, r3b);
    conn_kernel<<<dim3(40, 16), 256, 0, stream>>>(r3b, conn_W, conn_b, d_out, maskw);
}